// Round 1
// baseline (462.365 us; speedup 1.0000x reference)
//
#include <hip/hip_runtime.h>
#include <stdint.h>

typedef __attribute__((ext_vector_type(8))) __bf16 bf16x8;
typedef __attribute__((ext_vector_type(4))) float f32x4;

#define DEV __device__ __forceinline__

DEV unsigned short f2bf(float f) {
  union { float f; uint32_t u; } v; v.f = f;
  return (unsigned short)((v.u + 0x7fffu + ((v.u >> 16) & 1u)) >> 16);
}

DEV void gld16(const void* g, void* l) {
  __builtin_amdgcn_global_load_lds(
      (const __attribute__((address_space(1))) uint32_t*)g,
      (__attribute__((address_space(3))) uint32_t*)l, 16, 0, 0);
}

// ---------------- convert x fp32 -> bf16 (8 elems/thread) ----------------
__global__ __launch_bounds__(256) void k_cvt_x(const float* __restrict__ x,
                                               unsigned short* __restrict__ xb) {
  size_t t = (size_t)blockIdx.x * 256 + threadIdx.x;
  const float4* xv = (const float4*)x;
  float4 a = xv[t * 2], b = xv[t * 2 + 1];
  union { unsigned short s[8]; uint4 v; } u;
  u.s[0] = f2bf(a.x); u.s[1] = f2bf(a.y); u.s[2] = f2bf(a.z); u.s[3] = f2bf(a.w);
  u.s[4] = f2bf(b.x); u.s[5] = f2bf(b.y); u.s[6] = f2bf(b.z); u.s[7] = f2bf(b.w);
  *(uint4*)&xb[t * 8] = u.v;
}

// -------- transpose+convert weights: W[k][n] fp32 -> Wt[n][k] bf16 --------
__global__ void k_cvt_w(const float* __restrict__ W0, const float* __restrict__ W1,
                        const float* __restrict__ W2, const float* __restrict__ W3,
                        unsigned short* __restrict__ out) {
  const int z = blockIdx.z;
  const float* W = (z == 0) ? W0 : (z == 1) ? W1 : (z == 2) ? W2 : W3;
  unsigned short* Wt = out + (size_t)z * 1048576;
  __shared__ float tile[32][33];
  const int n0 = blockIdx.x * 32, k0 = blockIdx.y * 32;
  const int tx = threadIdx.x, ty = threadIdx.y;
#pragma unroll
  for (int i = 0; i < 4; i++)
    tile[ty * 4 + i][tx] = W[(size_t)(k0 + ty * 4 + i) * 1024 + n0 + tx];
  __syncthreads();
#pragma unroll
  for (int i = 0; i < 4; i++)
    Wt[(size_t)(n0 + ty * 4 + i) * 1024 + k0 + tx] = f2bf(tile[tx][ty * 4 + i]);
}

// ---------------- 128x128 bf16 GEMM, K=1024, m97-style ----------------
// MODE 0: C = A*Wt^T + bias, fused maxpool over row pairs, bf16 out in
//         [bh][s2][d] layout (z selects q/k/v).
// MODE 1: C = A*Wt^T + bias, fp32 out row-major.
template <int MODE>
__global__ __launch_bounds__(256) void k_gemm(
    const unsigned short* __restrict__ A,
    const unsigned short* __restrict__ Bt0, const unsigned short* __restrict__ Bt1,
    const unsigned short* __restrict__ Bt2,
    const float* __restrict__ bias0, const float* __restrict__ bias1,
    const float* __restrict__ bias2,
    unsigned short* __restrict__ out0, unsigned short* __restrict__ out1,
    unsigned short* __restrict__ out2,
    float* __restrict__ fout) {
  const int tid = threadIdx.x;
  const int n0 = blockIdx.x * 128, m0 = blockIdx.y * 128;
  const unsigned short* Bt = Bt0;
  const float* bias = bias0;
  unsigned short* OP = out0;
  if (MODE == 0) {
    int z = blockIdx.z;
    Bt = (z == 0) ? Bt0 : (z == 1) ? Bt1 : Bt2;
    bias = (z == 0) ? bias0 : (z == 1) ? bias1 : bias2;
    OP = (z == 0) ? out0 : (z == 1) ? out1 : out2;
  }

  __shared__ __align__(16) unsigned short lA[128 * 64];
  __shared__ __align__(16) unsigned short lB[128 * 64];

  const int lane = tid & 63, w = tid >> 6;
  const int wr = w >> 1, wc = w & 1;
  const int r = lane & 15, qd = lane >> 4;
  const int srow = tid >> 3, sg = tid & 7;

  f32x4 acc[4][4];
#pragma unroll
  for (int i = 0; i < 4; i++)
#pragma unroll
    for (int j = 0; j < 4; j++) acc[i][j] = (f32x4){0.f, 0.f, 0.f, 0.f};

  for (int k0 = 0; k0 < 1024; k0 += 64) {
    __syncthreads();
#pragma unroll
    for (int p = 0; p < 4; p++) {
      int row = p * 32 + srow;
      int gs = sg ^ (row & 7);  // XOR-swizzle at 16B granules: bank-conflict-free frags
      gld16(&A[(size_t)(m0 + row) * 1024 + k0 + gs * 8], &lA[row * 64 + sg * 8]);
      gld16(&Bt[(size_t)(n0 + row) * 1024 + k0 + gs * 8], &lB[row * 64 + sg * 8]);
    }
    __syncthreads();
#pragma unroll
    for (int kf = 0; kf < 2; kf++) {
      bf16x8 af[4], bfr[4];
#pragma unroll
      for (int mt = 0; mt < 4; mt++) {
        int row = wr * 64 + mt * 16 + r;
        int lg = (kf * 4 + qd) ^ (row & 7);
        af[mt] = *(const bf16x8*)&lA[row * 64 + lg * 8];
      }
#pragma unroll
      for (int nt = 0; nt < 4; nt++) {
        int row = wc * 64 + nt * 16 + r;
        int lg = (kf * 4 + qd) ^ (row & 7);
        bfr[nt] = *(const bf16x8*)&lB[row * 64 + lg * 8];
      }
#pragma unroll
      for (int mt = 0; mt < 4; mt++)
#pragma unroll
        for (int nt = 0; nt < 4; nt++)
          acc[mt][nt] = __builtin_amdgcn_mfma_f32_16x16x32_bf16(af[mt], bfr[nt],
                                                               acc[mt][nt], 0, 0, 0);
    }
  }

#pragma unroll
  for (int nt = 0; nt < 4; nt++) {
    int n = n0 + wc * 64 + nt * 16 + r;
    float bv = bias[n];
    if (MODE == 0) {
      int h = n >> 6, d = n & 63;
#pragma unroll
      for (int mt = 0; mt < 4; mt++) {
        int mg = m0 + wr * 64 + mt * 16 + qd * 4;  // rows mg..mg+3 (in-lane)
        int b = mg >> 12, s2 = (mg & 4095) >> 1;
        f32x4 a = acc[mt][nt];
        size_t base = ((size_t)(b * 16 + h) * 2048 + s2) * 64 + d;
        OP[base] = f2bf(fmaxf(a.x, a.y) + bv);       // pooled row s2
        OP[base + 64] = f2bf(fmaxf(a.z, a.w) + bv);  // pooled row s2+1
      }
    } else {
#pragma unroll
      for (int mt = 0; mt < 4; mt++) {
        int mg = m0 + wr * 64 + mt * 16 + qd * 4;
        f32x4 a = acc[mt][nt];
        fout[(size_t)(mg + 0) * 1024 + n] = a.x + bv;
        fout[(size_t)(mg + 1) * 1024 + n] = a.y + bv;
        fout[(size_t)(mg + 2) * 1024 + n] = a.z + bv;
        fout[(size_t)(mg + 3) * 1024 + n] = a.w + bv;
      }
    }
  }
}

// ---------------- V [bh][s2][d] -> Vt [bh][d][s2] ----------------
__global__ __launch_bounds__(256) void k_trV(const unsigned short* __restrict__ Vp,
                                             unsigned short* __restrict__ Vt) {
  const int bh = blockIdx.y, t0 = blockIdx.x * 64;
  const int tid = threadIdx.x;
  const int sc = tid >> 3, sg = tid & 7;
  __shared__ __align__(16) unsigned short tile[64 * 72];
#pragma unroll
  for (int c = 0; c < 2; c++) {
    int row = c * 32 + sc;
    *(uint4*)&tile[row * 72 + sg * 8] =
        *(const uint4*)&Vp[((size_t)bh * 2048 + t0 + row) * 64 + sg * 8];
  }
  __syncthreads();
#pragma unroll
  for (int c = 0; c < 2; c++) {
    int d = c * 32 + sc;
    union { unsigned short s[8]; uint4 v; } u;
#pragma unroll
    for (int j = 0; j < 8; j++) u.s[j] = tile[(sg * 8 + j) * 72 + d];
    *(uint4*)&Vt[((size_t)bh * 64 + d) * 2048 + t0 + sg * 8] = u.v;
  }
}

// ---------------- flash attention + fused q-maxpool ----------------
// grid (32 qtiles, 64 bh); block 256 = 4 waves, wave w owns q rows q0+16w..+16
__global__ __launch_bounds__(256) void k_attn(const unsigned short* __restrict__ Qp,
                                              const unsigned short* __restrict__ Kp,
                                              const unsigned short* __restrict__ Vt,
                                              unsigned short* __restrict__ Am) {
  const int tid = threadIdx.x;
  const int qt = blockIdx.x, bh = blockIdx.y;
  const int w = tid >> 6, lane = tid & 63;
  const int r = lane & 15, qd = lane >> 4;
  const int sc = tid >> 3, sg = tid & 7;

  __shared__ __align__(16) unsigned short lK[64 * 72];      // [kpos][d], 144B stride
  __shared__ __align__(16) unsigned short lV[64 * 72];      // [d][kpos]
  __shared__ __align__(16) unsigned short lP[4][16 * 72];   // per-wave P [qrow][kpos]

  const int q0 = qt * 64;
  const int qrow = q0 + w * 16 + r;
  const size_t qbase = ((size_t)bh * 2048 + qrow) * 64;
  bf16x8 aq0 = *(const bf16x8*)&Qp[qbase + qd * 8];
  bf16x8 aq1 = *(const bf16x8*)&Qp[qbase + 32 + qd * 8];

  float mr[4], lr[4];
  f32x4 accO[4];
#pragma unroll
  for (int i = 0; i < 4; i++) {
    mr[i] = -1e30f; lr[i] = 0.f; accO[i] = (f32x4){0.f, 0.f, 0.f, 0.f};
  }

  for (int kb = 0; kb < 2048; kb += 64) {
    __syncthreads();
#pragma unroll
    for (int c = 0; c < 2; c++) {
      int row = c * 32 + sc;
      *(uint4*)&lK[row * 72 + sg * 8] =
          *(const uint4*)&Kp[((size_t)bh * 2048 + kb + row) * 64 + sg * 8];
      *(uint4*)&lV[row * 72 + sg * 8] =
          *(const uint4*)&Vt[((size_t)bh * 64 + row) * 2048 + kb + sg * 8];
    }
    __syncthreads();

    f32x4 s[4];
#pragma unroll
    for (int nt = 0; nt < 4; nt++) {
      s[nt] = (f32x4){0.f, 0.f, 0.f, 0.f};
      bf16x8 bk0 = *(const bf16x8*)&lK[(nt * 16 + r) * 72 + qd * 8];
      bf16x8 bk1 = *(const bf16x8*)&lK[(nt * 16 + r) * 72 + 32 + qd * 8];
      s[nt] = __builtin_amdgcn_mfma_f32_16x16x32_bf16(aq0, bk0, s[nt], 0, 0, 0);
      s[nt] = __builtin_amdgcn_mfma_f32_16x16x32_bf16(aq1, bk1, s[nt], 0, 0, 0);
    }

    // online softmax (scale 1/8 folded into exp); rows live in quad reg-slots
    float rm[4];
#pragma unroll
    for (int g = 0; g < 4; g++)
      rm[g] = fmaxf(fmaxf(s[0][g], s[1][g]), fmaxf(s[2][g], s[3][g]));
#pragma unroll
    for (int off = 1; off < 16; off <<= 1)
#pragma unroll
      for (int g = 0; g < 4; g++)
        rm[g] = fmaxf(rm[g], __shfl_xor(rm[g], off, 64));

    float al[4];
#pragma unroll
    for (int g = 0; g < 4; g++) {
      float mn = fmaxf(mr[g], rm[g]);
      al[g] = __expf((mr[g] - mn) * 0.125f);
      mr[g] = mn;
    }
    float p[4][4];
#pragma unroll
    for (int nt = 0; nt < 4; nt++)
#pragma unroll
      for (int g = 0; g < 4; g++)
        p[nt][g] = __expf((s[nt][g] - mr[g]) * 0.125f);
#pragma unroll
    for (int g = 0; g < 4; g++)
      lr[g] = lr[g] * al[g] + (p[0][g] + p[1][g] + p[2][g] + p[3][g]);
#pragma unroll
    for (int nt = 0; nt < 4; nt++) {
      accO[nt][0] *= al[0]; accO[nt][1] *= al[1];
      accO[nt][2] *= al[2]; accO[nt][3] *= al[3];
    }

    // P: C-layout -> LDS -> A-layout (wave-private, no barrier needed)
#pragma unroll
    for (int nt = 0; nt < 4; nt++)
#pragma unroll
      for (int g = 0; g < 4; g++)
        lP[w][(qd * 4 + g) * 72 + nt * 16 + r] = f2bf(p[nt][g]);

    bf16x8 ap0 = *(const bf16x8*)&lP[w][r * 72 + qd * 8];
    bf16x8 ap1 = *(const bf16x8*)&lP[w][r * 72 + 32 + qd * 8];
#pragma unroll
    for (int nt = 0; nt < 4; nt++) {
      bf16x8 bv0 = *(const bf16x8*)&lV[(nt * 16 + r) * 72 + qd * 8];
      bf16x8 bv1 = *(const bf16x8*)&lV[(nt * 16 + r) * 72 + 32 + qd * 8];
      accO[nt] = __builtin_amdgcn_mfma_f32_16x16x32_bf16(ap0, bv0, accO[nt], 0, 0, 0);
      accO[nt] = __builtin_amdgcn_mfma_f32_16x16x32_bf16(ap1, bv1, accO[nt], 0, 0, 0);
    }
  }

  float inv[4];
#pragma unroll
  for (int g = 0; g < 4; g++) {
    float l = lr[g];
#pragma unroll
    for (int off = 1; off < 16; off <<= 1) l += __shfl_xor(l, off, 64);
    inv[g] = 1.f / l;
  }
  // normalize, fused q-pool (in-lane reg pairs), write [bh][s4][d] == final GEMM A
#pragma unroll
  for (int nt = 0; nt < 4; nt++) {
    int d = nt * 16 + r;
    int s4 = (q0 + w * 16 + qd * 4) >> 1;
    float o0 = fmaxf(accO[nt][0] * inv[0], accO[nt][1] * inv[1]);
    float o1 = fmaxf(accO[nt][2] * inv[2], accO[nt][3] * inv[3]);
    size_t base = ((size_t)bh * 1024 + s4) * 64 + d;
    Am[base] = f2bf(o0);
    Am[base + 64] = f2bf(o1);
  }
}

extern "C" void kernel_launch(void* const* d_in, const int* in_sizes, int n_in,
                              void* d_out, int out_size, void* d_ws, size_t ws_size,
                              hipStream_t stream) {
  const float* x  = (const float*)d_in[0];
  const float* Wq = (const float*)d_in[1];
  const float* bq = (const float*)d_in[2];
  const float* Wk = (const float*)d_in[3];
  const float* bk = (const float*)d_in[4];
  const float* Wv = (const float*)d_in[5];
  const float* bv = (const float*)d_in[6];
  const float* Wo = (const float*)d_in[7];
  const float* bo = (const float*)d_in[8];
  float* out = (float*)d_out;

  uint8_t* ws = (uint8_t*)d_ws;
  unsigned short* xb = (unsigned short*)(ws);              // 33,554,432 B
  unsigned short* Wt = (unsigned short*)(ws + 33554432);   //  8,388,608 B (4 weights)
  unsigned short* Qp = (unsigned short*)(ws + 41943040);   // 16,777,216 B
  unsigned short* Kp = (unsigned short*)(ws + 58720256);   // 16,777,216 B
  unsigned short* Vp = (unsigned short*)(ws + 75497472);   // 16,777,216 B
  unsigned short* Am = (unsigned short*)(ws + 92274688);   //  8,388,608 B
  unsigned short* Vt = (unsigned short*)(ws);              // aliases xb (x dead by then)

  k_cvt_x<<<8192, 256, 0, stream>>>(x, xb);
  k_cvt_w<<<dim3(32, 32, 4), dim3(32, 8), 0, stream>>>(Wq, Wk, Wv, Wo, Wt);
  k_gemm<0><<<dim3(8, 128, 3), 256, 0, stream>>>(
      xb, Wt, Wt + 1048576, Wt + 2097152, bq, bk, bv, Qp, Kp, Vp, nullptr);
  k_trV<<<dim3(32, 64), 256, 0, stream>>>(Vp, Vt);
  k_attn<<<dim3(32, 64), 256, 0, stream>>>(Qp, Kp, Vt, Am);
  k_gemm<1><<<dim3(8, 32, 1), 256, 0, stream>>>(
      Am, Wt + 3145728, nullptr, nullptr, bo, nullptr, nullptr,
      nullptr, nullptr, nullptr, out);
}

// Round 2
// 398.675 us; speedup vs baseline: 1.1598x; 1.1598x over previous
//
#include <hip/hip_runtime.h>
#include <stdint.h>

typedef __attribute__((ext_vector_type(8))) __bf16 bf16x8;
typedef __attribute__((ext_vector_type(4))) float f32x4;

#define DEV __device__ __forceinline__

DEV unsigned short f2bf(float f) {
  union { float f; uint32_t u; } v; v.f = f;
  return (unsigned short)((v.u + 0x7fffu + ((v.u >> 16) & 1u)) >> 16);
}

// pack two fp32 -> bf16 pair (round-half-up) in one v_perm
DEV uint32_t pk2bf(float lo, float hi) {
  union { float f; uint32_t u; } a, b;
  a.f = lo; b.f = hi;
  return __builtin_amdgcn_perm(b.u + 0x8000u, a.u + 0x8000u, 0x07060302u);
}

DEV void gld16(const void* g, void* l) {
  __builtin_amdgcn_global_load_lds(
      (const __attribute__((address_space(1))) uint32_t*)g,
      (__attribute__((address_space(3))) uint32_t*)l, 16, 0, 0);
}

// ---------------- convert x fp32 -> bf16 (8 elems/thread) ----------------
__global__ __launch_bounds__(256) void k_cvt_x(const float* __restrict__ x,
                                               unsigned short* __restrict__ xb) {
  size_t t = (size_t)blockIdx.x * 256 + threadIdx.x;
  const float4* xv = (const float4*)x;
  float4 a = xv[t * 2], b = xv[t * 2 + 1];
  union { unsigned short s[8]; uint4 v; } u;
  u.s[0] = f2bf(a.x); u.s[1] = f2bf(a.y); u.s[2] = f2bf(a.z); u.s[3] = f2bf(a.w);
  u.s[4] = f2bf(b.x); u.s[5] = f2bf(b.y); u.s[6] = f2bf(b.z); u.s[7] = f2bf(b.w);
  *(uint4*)&xb[t * 8] = u.v;
}

// -------- transpose+convert weights: W[k][n] fp32 -> Wt[n][k] bf16 --------
__global__ void k_cvt_w(const float* __restrict__ W0, const float* __restrict__ W1,
                        const float* __restrict__ W2, const float* __restrict__ W3,
                        unsigned short* __restrict__ out) {
  const int z = blockIdx.z;
  const float* W = (z == 0) ? W0 : (z == 1) ? W1 : (z == 2) ? W2 : W3;
  unsigned short* Wt = out + (size_t)z * 1048576;
  __shared__ float tile[32][33];
  const int n0 = blockIdx.x * 32, k0 = blockIdx.y * 32;
  const int tx = threadIdx.x, ty = threadIdx.y;
#pragma unroll
  for (int i = 0; i < 4; i++)
    tile[ty * 4 + i][tx] = W[(size_t)(k0 + ty * 4 + i) * 1024 + n0 + tx];
  __syncthreads();
#pragma unroll
  for (int i = 0; i < 4; i++)
    Wt[(size_t)(n0 + ty * 4 + i) * 1024 + k0 + tx] = f2bf(tile[tx][ty * 4 + i]);
}

// ---------------- 128x128 bf16 GEMM, K=1024, m97-style ----------------
template <int MODE>
__global__ __launch_bounds__(256) void k_gemm(
    const unsigned short* __restrict__ A,
    const unsigned short* __restrict__ Bt0, const unsigned short* __restrict__ Bt1,
    const unsigned short* __restrict__ Bt2,
    const float* __restrict__ bias0, const float* __restrict__ bias1,
    const float* __restrict__ bias2,
    unsigned short* __restrict__ out0, unsigned short* __restrict__ out1,
    unsigned short* __restrict__ out2,
    float* __restrict__ fout) {
  const int tid = threadIdx.x;
  const int n0 = blockIdx.x * 128, m0 = blockIdx.y * 128;
  const unsigned short* Bt = Bt0;
  const float* bias = bias0;
  unsigned short* OP = out0;
  if (MODE == 0) {
    int z = blockIdx.z;
    Bt = (z == 0) ? Bt0 : (z == 1) ? Bt1 : Bt2;
    bias = (z == 0) ? bias0 : (z == 1) ? bias1 : bias2;
    OP = (z == 0) ? out0 : (z == 1) ? out1 : out2;
  }

  __shared__ __align__(16) unsigned short lA[128 * 64];
  __shared__ __align__(16) unsigned short lB[128 * 64];

  const int lane = tid & 63, w = tid >> 6;
  const int wr = w >> 1, wc = w & 1;
  const int r = lane & 15, qd = lane >> 4;
  const int srow = tid >> 3, sg = tid & 7;

  f32x4 acc[4][4];
#pragma unroll
  for (int i = 0; i < 4; i++)
#pragma unroll
    for (int j = 0; j < 4; j++) acc[i][j] = (f32x4){0.f, 0.f, 0.f, 0.f};

  for (int k0 = 0; k0 < 1024; k0 += 64) {
    __syncthreads();
#pragma unroll
    for (int p = 0; p < 4; p++) {
      int row = p * 32 + srow;
      int gs = sg ^ (row & 7);
      gld16(&A[(size_t)(m0 + row) * 1024 + k0 + gs * 8], &lA[row * 64 + sg * 8]);
      gld16(&Bt[(size_t)(n0 + row) * 1024 + k0 + gs * 8], &lB[row * 64 + sg * 8]);
    }
    __syncthreads();
#pragma unroll
    for (int kf = 0; kf < 2; kf++) {
      bf16x8 af[4], bfr[4];
#pragma unroll
      for (int mt = 0; mt < 4; mt++) {
        int row = wr * 64 + mt * 16 + r;
        int lg = (kf * 4 + qd) ^ (row & 7);
        af[mt] = *(const bf16x8*)&lA[row * 64 + lg * 8];
      }
#pragma unroll
      for (int nt = 0; nt < 4; nt++) {
        int row = wc * 64 + nt * 16 + r;
        int lg = (kf * 4 + qd) ^ (row & 7);
        bfr[nt] = *(const bf16x8*)&lB[row * 64 + lg * 8];
      }
#pragma unroll
      for (int mt = 0; mt < 4; mt++)
#pragma unroll
        for (int nt = 0; nt < 4; nt++)
          acc[mt][nt] = __builtin_amdgcn_mfma_f32_16x16x32_bf16(af[mt], bfr[nt],
                                                               acc[mt][nt], 0, 0, 0);
    }
  }

#pragma unroll
  for (int nt = 0; nt < 4; nt++) {
    int n = n0 + wc * 64 + nt * 16 + r;
    float bv = bias[n];
    if (MODE == 0) {
      int h = n >> 6, d = n & 63;
#pragma unroll
      for (int mt = 0; mt < 4; mt++) {
        int mg = m0 + wr * 64 + mt * 16 + qd * 4;
        int b = mg >> 12, s2 = (mg & 4095) >> 1;
        f32x4 a = acc[mt][nt];
        size_t base = ((size_t)(b * 16 + h) * 2048 + s2) * 64 + d;
        OP[base] = f2bf(fmaxf(a.x, a.y) + bv);
        OP[base + 64] = f2bf(fmaxf(a.z, a.w) + bv);
      }
    } else {
#pragma unroll
      for (int mt = 0; mt < 4; mt++) {
        int mg = m0 + wr * 64 + mt * 16 + qd * 4;
        f32x4 a = acc[mt][nt];
        fout[(size_t)(mg + 0) * 1024 + n] = a.x + bv;
        fout[(size_t)(mg + 1) * 1024 + n] = a.y + bv;
        fout[(size_t)(mg + 2) * 1024 + n] = a.z + bv;
        fout[(size_t)(mg + 3) * 1024 + n] = a.w + bv;
      }
    }
  }
}

// ---------------- V [bh][s2][d] -> Vt [bh][d][s2] ----------------
__global__ __launch_bounds__(256) void k_trV(const unsigned short* __restrict__ Vp,
                                             unsigned short* __restrict__ Vt) {
  const int bh = blockIdx.y, t0 = blockIdx.x * 64;
  const int tid = threadIdx.x;
  const int sc = tid >> 3, sg = tid & 7;
  __shared__ __align__(16) unsigned short tile[64 * 72];
#pragma unroll
  for (int c = 0; c < 2; c++) {
    int row = c * 32 + sc;
    *(uint4*)&tile[row * 72 + sg * 8] =
        *(const uint4*)&Vp[((size_t)bh * 2048 + t0 + row) * 64 + sg * 8];
  }
  __syncthreads();
#pragma unroll
  for (int c = 0; c < 2; c++) {
    int d = c * 32 + sc;
    union { unsigned short s[8]; uint4 v; } u;
#pragma unroll
    for (int j = 0; j < 8; j++) u.s[j] = tile[(sg * 8 + j) * 72 + d];
    *(uint4*)&Vt[((size_t)bh * 64 + d) * 2048 + t0 + sg * 8] = u.v;
  }
}

// ---------------- flash attention (no-max softmax) + fused q-maxpool ----------------
// S^T = K*Q^T so P exits with k in-lane -> b64 packed LDS writes, b128 A-frag reads.
// grid (32 qtiles, 64 bh); block 256 = 4 waves; wave owns 16 q rows.
__global__ __launch_bounds__(256) void k_attn(const unsigned short* __restrict__ Qp,
                                              const unsigned short* __restrict__ Kp,
                                              const unsigned short* __restrict__ Vt,
                                              unsigned short* __restrict__ Am) {
  const int tid = threadIdx.x;
  const int qt = blockIdx.x, bh = blockIdx.y;
  const int w = tid >> 6, lane = tid & 63;
  const int r = lane & 15, qd = lane >> 4;
  const int srow = tid >> 3, sg = tid & 7;

  __shared__ __align__(16) unsigned short lK[64 * 64];   // [kpos][d]  XOR-swizzled 16B granules
  __shared__ __align__(16) unsigned short lV[64 * 64];   // [d][kpos]  XOR-swizzled
  __shared__ __align__(16) unsigned short lP[4][16 * 80];// per-wave P [q][k], 160B rows, swizzled

  const int q0 = qt * 64;
  const int qrow = q0 + w * 16 + r;
  const size_t qbase = ((size_t)bh * 2048 + qrow) * 64;
  const bf16x8 bq0 = *(const bf16x8*)&Qp[qbase + qd * 8];       // B-frag dims 0..31
  const bf16x8 bq1 = *(const bf16x8*)&Qp[qbase + 32 + qd * 8];  // dims 32..63

  const unsigned short* Kg = Kp + (size_t)bh * 2048 * 64;
  const unsigned short* Vg = Vt + (size_t)bh * 64 * 2048;

  // exp2-space: p = 2^(s*0.125*log2e - 0.5) ; the -0.5 bias cancels in O = sum(pV)/sum(p)
  const float K2 = 0.125f * 1.44269504f;

  float lsum = 0.f;
  f32x4 accO[4];
#pragma unroll
  for (int i = 0; i < 4; i++) accO[i] = (f32x4){0.f, 0.f, 0.f, 0.f};

  char* lPw = (char*)&lP[w][0];

  for (int kb = 0; kb < 2048; kb += 64) {
    __syncthreads();
#pragma unroll
    for (int c = 0; c < 2; c++) {
      int row = c * 32 + srow;
      int gs = sg ^ (row & 7);
      gld16(&Kg[(size_t)(kb + row) * 64 + gs * 8], &lK[row * 64 + sg * 8]);
      gld16(&Vg[(size_t)row * 2048 + kb + gs * 8], &lV[row * 64 + sg * 8]);
    }
    __syncthreads();

    // S^T = K · Q^T : C col = q (=r), row = kpos (=qd*4+g)
    f32x4 s[4];
#pragma unroll
    for (int mt = 0; mt < 4; mt++) {
      int row = mt * 16 + r;  // kpos
      int lg0 = qd ^ (row & 7), lg1 = (4 + qd) ^ (row & 7);
      bf16x8 ak0 = *(const bf16x8*)&lK[row * 64 + lg0 * 8];
      bf16x8 ak1 = *(const bf16x8*)&lK[row * 64 + lg1 * 8];
      s[mt] = (f32x4){0.f, 0.f, 0.f, 0.f};
      s[mt] = __builtin_amdgcn_mfma_f32_16x16x32_bf16(ak0, bq0, s[mt], 0, 0, 0);
      s[mt] = __builtin_amdgcn_mfma_f32_16x16x32_bf16(ak1, bq1, s[mt], 0, 0, 0);
    }

    // p = exp2(fma) ; pack pairs ; one b64 write per mt (granule-XOR-swizzled)
#pragma unroll
    for (int mt = 0; mt < 4; mt++) {
      float p0 = __builtin_amdgcn_exp2f(fmaf(s[mt][0], K2, -0.5f));
      float p1 = __builtin_amdgcn_exp2f(fmaf(s[mt][1], K2, -0.5f));
      float p2 = __builtin_amdgcn_exp2f(fmaf(s[mt][2], K2, -0.5f));
      float p3 = __builtin_amdgcn_exp2f(fmaf(s[mt][3], K2, -0.5f));
      lsum += (p0 + p1) + (p2 + p3);
      uint2 dw; dw.x = pk2bf(p0, p1); dw.y = pk2bf(p2, p3);
      // logical granule 2*mt + (qd>>1), half (qd&1); phys granule ^= (r&7)
      int off = r * 160 + (((2 * mt + (qd >> 1)) ^ (r & 7)) << 4) + ((qd & 1) << 3);
      *(uint2*)(lPw + off) = dw;
    }

    // A-frags of P (wave-private: compiler's lgkmcnt handles RAW, no barrier)
    bf16x8 ap0 = *(const bf16x8*)(lPw + r * 160 + ((qd ^ (r & 7)) << 4));
    bf16x8 ap1 = *(const bf16x8*)(lPw + r * 160 + (((4 + qd) ^ (r & 7)) << 4));

#pragma unroll
    for (int nt = 0; nt < 4; nt++) {
      int row = nt * 16 + r;  // d
      int lg0 = qd ^ (row & 7), lg1 = (4 + qd) ^ (row & 7);
      bf16x8 bv0 = *(const bf16x8*)&lV[row * 64 + lg0 * 8];
      bf16x8 bv1 = *(const bf16x8*)&lV[row * 64 + lg1 * 8];
      accO[nt] = __builtin_amdgcn_mfma_f32_16x16x32_bf16(ap0, bv0, accO[nt], 0, 0, 0);
      accO[nt] = __builtin_amdgcn_mfma_f32_16x16x32_bf16(ap1, bv1, accO[nt], 0, 0, 0);
    }
  }

  // l reduction: per-lane lsum covers q=r, k = own (mt,g) slots; sum over qd lanes
  lsum += __shfl_xor(lsum, 16, 64);
  lsum += __shfl_xor(lsum, 32, 64);
  float linv = 1.f / lsum;  // valid for q-row = r on every lane
  float inv[4];
#pragma unroll
  for (int g = 0; g < 4; g++) inv[g] = __shfl(linv, qd * 4 + g, 64);

  // normalize, fused q-pool (in-lane reg pairs), write [bh][s4][d]
#pragma unroll
  for (int nt = 0; nt < 4; nt++) {
    int d = nt * 16 + r;
    int s4 = (q0 + w * 16 + qd * 4) >> 1;
    float o0 = fmaxf(accO[nt][0] * inv[0], accO[nt][1] * inv[1]);
    float o1 = fmaxf(accO[nt][2] * inv[2], accO[nt][3] * inv[3]);
    size_t base = ((size_t)bh * 1024 + s4) * 64 + d;
    Am[base] = f2bf(o0);
    Am[base + 64] = f2bf(o1);
  }
}

extern "C" void kernel_launch(void* const* d_in, const int* in_sizes, int n_in,
                              void* d_out, int out_size, void* d_ws, size_t ws_size,
                              hipStream_t stream) {
  const float* x  = (const float*)d_in[0];
  const float* Wq = (const float*)d_in[1];
  const float* bq = (const float*)d_in[2];
  const float* Wk = (const float*)d_in[3];
  const float* bk = (const float*)d_in[4];
  const float* Wv = (const float*)d_in[5];
  const float* bv = (const float*)d_in[6];
  const float* Wo = (const float*)d_in[7];
  const float* bo = (const float*)d_in[8];
  float* out = (float*)d_out;

  uint8_t* ws = (uint8_t*)d_ws;
  unsigned short* xb = (unsigned short*)(ws);              // 33,554,432 B
  unsigned short* Wt = (unsigned short*)(ws + 33554432);   //  8,388,608 B (4 weights)
  unsigned short* Qp = (unsigned short*)(ws + 41943040);   // 16,777,216 B
  unsigned short* Kp = (unsigned short*)(ws + 58720256);   // 16,777,216 B
  unsigned short* Vp = (unsigned short*)(ws + 75497472);   // 16,777,216 B
  unsigned short* Am = (unsigned short*)(ws + 92274688);   //  8,388,608 B
  unsigned short* Vt = (unsigned short*)(ws);              // aliases xb (x dead by then)

  k_cvt_x<<<8192, 256, 0, stream>>>(x, xb);
  k_cvt_w<<<dim3(32, 32, 4), dim3(32, 8), 0, stream>>>(Wq, Wk, Wv, Wo, Wt);
  k_gemm<0><<<dim3(8, 128, 3), 256, 0, stream>>>(
      xb, Wt, Wt + 1048576, Wt + 2097152, bq, bk, bv, Qp, Kp, Vp, nullptr);
  k_trV<<<dim3(32, 64), 256, 0, stream>>>(Vp, Vt);
  k_attn<<<dim3(32, 64), 256, 0, stream>>>(Qp, Kp, Vt, Am);
  k_gemm<1><<<dim3(8, 32, 1), 256, 0, stream>>>(
      Am, Wt + 3145728, nullptr, nullptr, bo, nullptr, nullptr,
      nullptr, nullptr, nullptr, out);
}

// Round 3
// 376.967 us; speedup vs baseline: 1.2265x; 1.0576x over previous
//
#include <hip/hip_runtime.h>
#include <stdint.h>

typedef __attribute__((ext_vector_type(8))) __bf16 bf16x8;
typedef __attribute__((ext_vector_type(4))) float f32x4;
typedef __attribute__((ext_vector_type(8))) int i32x8;

#define DEV __device__ __forceinline__

DEV unsigned short f2bf(float f) {
  union { float f; uint32_t u; } v; v.f = f;
  return (unsigned short)((v.u + 0x7fffu + ((v.u >> 16) & 1u)) >> 16);
}

// pack two fp32 -> bf16 pair (round-half-up) in one v_perm
DEV uint32_t pk2bf(float lo, float hi) {
  union { float f; uint32_t u; } a, b;
  a.f = lo; b.f = hi;
  return __builtin_amdgcn_perm(b.u + 0x8000u, a.u + 0x8000u, 0x07060302u);
}

DEV void gld16(const void* g, void* l) {
  __builtin_amdgcn_global_load_lds(
      (const __attribute__((address_space(1))) uint32_t*)g,
      (__attribute__((address_space(3))) uint32_t*)l, 16, 0, 0);
}

union Frag8 { i32x8 v; uint4 q[2]; };

// ---------------- convert x fp32 -> fp8 e4m3 (8 elems/thread) ----------------
__global__ __launch_bounds__(256) void k_cvt_x(const float* __restrict__ x,
                                               uint8_t* __restrict__ x8) {
  size_t t = (size_t)blockIdx.x * 256 + threadIdx.x;
  const float4* xv = (const float4*)x;
  float4 a = xv[t * 2], b = xv[t * 2 + 1];
  int lo = 0, hi = 0;
  lo = __builtin_amdgcn_cvt_pk_fp8_f32(a.x, a.y, lo, false);
  lo = __builtin_amdgcn_cvt_pk_fp8_f32(a.z, a.w, lo, true);
  hi = __builtin_amdgcn_cvt_pk_fp8_f32(b.x, b.y, hi, false);
  hi = __builtin_amdgcn_cvt_pk_fp8_f32(b.z, b.w, hi, true);
  int2 pk; pk.x = lo; pk.y = hi;
  *(int2*)&x8[t * 8] = pk;
}

// -------- weights: W[k][n] fp32 -> z<3: fp8 Wt[n][k] (x32); z=3: bf16 Wt[n][k] --------
__global__ void k_cvt_w(const float* __restrict__ W0, const float* __restrict__ W1,
                        const float* __restrict__ W2, const float* __restrict__ W3,
                        uint8_t* __restrict__ W8, unsigned short* __restrict__ WoT) {
  const int z = blockIdx.z;
  const float* W = (z == 0) ? W0 : (z == 1) ? W1 : (z == 2) ? W2 : W3;
  __shared__ float tile[32][33];
  const int n0 = blockIdx.x * 32, k0 = blockIdx.y * 32;
  const int tx = threadIdx.x, ty = threadIdx.y;
  const int tid = ty * 32 + tx;
#pragma unroll
  for (int i = 0; i < 4; i++)
    tile[ty * 4 + i][tx] = W[(size_t)(k0 + ty * 4 + i) * 1024 + n0 + tx];
  __syncthreads();
  if (z < 3) {
    int nn = tid >> 3, kg = tid & 7;  // tile[kk][nn] = W[k0+kk][n0+nn]
    int w_ = 0;
    w_ = __builtin_amdgcn_cvt_pk_fp8_f32(32.f * tile[kg * 4 + 0][nn],
                                         32.f * tile[kg * 4 + 1][nn], w_, false);
    w_ = __builtin_amdgcn_cvt_pk_fp8_f32(32.f * tile[kg * 4 + 2][nn],
                                         32.f * tile[kg * 4 + 3][nn], w_, true);
    *(uint32_t*)&W8[(size_t)z * 1048576 + (size_t)(n0 + nn) * 1024 + k0 + kg * 4] =
        (uint32_t)w_;
  } else {
#pragma unroll
    for (int i = 0; i < 4; i++)
      WoT[(size_t)(n0 + ty * 4 + i) * 1024 + k0 + tx] = f2bf(tile[tx][ty * 4 + i]);
  }
}

// ------- QKV projection: MX-fp8 128x128 tile, BK=128, K=1024, fused pool -------
// z=0 -> Qp [bh][s2][d], z=1 -> Kp, z=2 -> Vt [bh][d][s2] (transposed directly)
__global__ __launch_bounds__(256) void k_gemm_qkv(
    const uint8_t* __restrict__ A, const uint8_t* __restrict__ W8,
    const float* __restrict__ bq, const float* __restrict__ bk,
    const float* __restrict__ bv,
    unsigned short* __restrict__ Qp, unsigned short* __restrict__ Kp,
    unsigned short* __restrict__ Vt) {
  const int tid = threadIdx.x;
  const int n0 = blockIdx.x * 128, m0 = blockIdx.y * 128;
  const int z = blockIdx.z;
  const uint8_t* Bt = W8 + (size_t)z * 1048576;
  const float* bias = (z == 0) ? bq : (z == 1) ? bk : bv;

  __shared__ __align__(16) uint8_t lA[128 * 128];
  __shared__ __align__(16) uint8_t lB[128 * 128];

  const int lane = tid & 63, w = tid >> 6;
  const int wr = w >> 1, wc = w & 1;
  const int r = lane & 15, qd = lane >> 4;
  const int rl = lane >> 3, sg = lane & 7;

  f32x4 acc[4][4];
#pragma unroll
  for (int i = 0; i < 4; i++)
#pragma unroll
    for (int j = 0; j < 4; j++) acc[i][j] = (f32x4){0.f, 0.f, 0.f, 0.f};

  for (int k0 = 0; k0 < 1024; k0 += 128) {
    __syncthreads();
#pragma unroll
    for (int p = 0; p < 4; p++) {
      int row = (p * 4 + w) * 8 + rl;
      int g = sg ^ (row & 7);  // 16B-granule XOR swizzle
      gld16(&A[(size_t)(m0 + row) * 1024 + k0 + g * 16], &lA[row * 128 + sg * 16]);
      gld16(&Bt[(size_t)(n0 + row) * 1024 + k0 + g * 16], &lB[row * 128 + sg * 16]);
    }
    __syncthreads();
    Frag8 bfr[4];
#pragma unroll
    for (int nt = 0; nt < 4; nt++) {
      int row = wc * 64 + nt * 16 + r;
      int g0 = (2 * qd) ^ (row & 7), g1 = (2 * qd + 1) ^ (row & 7);
      bfr[nt].q[0] = *(const uint4*)&lB[row * 128 + g0 * 16];
      bfr[nt].q[1] = *(const uint4*)&lB[row * 128 + g1 * 16];
    }
#pragma unroll
    for (int mt = 0; mt < 4; mt++) {
      int row = wr * 64 + mt * 16 + r;
      int g0 = (2 * qd) ^ (row & 7), g1 = (2 * qd + 1) ^ (row & 7);
      Frag8 af;
      af.q[0] = *(const uint4*)&lA[row * 128 + g0 * 16];
      af.q[1] = *(const uint4*)&lA[row * 128 + g1 * 16];
#pragma unroll
      for (int nt = 0; nt < 4; nt++)
        acc[mt][nt] = __builtin_amdgcn_mfma_scale_f32_16x16x128_f8f6f4(
            af.v, bfr[nt].v, acc[mt][nt], 0, 0, 0, 0x7f7f7f7f, 0, 0x7f7f7f7f);
    }
  }

  unsigned short* OP = (z == 0) ? Qp : Kp;
#pragma unroll
  for (int nt = 0; nt < 4; nt++) {
    int n = n0 + wc * 64 + nt * 16 + r;
    float bv_ = bias[n];
    int h = n >> 6, d = n & 63;
#pragma unroll
    for (int mt = 0; mt < 4; mt++) {
      int mg = m0 + wr * 64 + mt * 16 + qd * 4;
      int b = mg >> 12, s2 = (mg & 4095) >> 1;
      int bh = b * 16 + h;
      f32x4 a = acc[mt][nt];
      float v0 = fmaxf(a.x, a.y) * 0.03125f + bv_;  // undo W x32 scale
      float v1 = fmaxf(a.z, a.w) * 0.03125f + bv_;
      if (z == 2) {
        uint32_t pk = (uint32_t)f2bf(v0) | ((uint32_t)f2bf(v1) << 16);
        *(uint32_t*)&Vt[((size_t)bh * 64 + d) * 2048 + s2] = pk;  // s2 even
      } else {
        size_t base = ((size_t)bh * 2048 + s2) * 64 + d;
        OP[base] = f2bf(v0);
        OP[base + 64] = f2bf(v1);
      }
    }
  }
}

// ---------------- final GEMM: out = Am(bf16) @ WoT^T + bo, fp32 out ----------------
__global__ __launch_bounds__(256) void k_gemm_out(
    const unsigned short* __restrict__ A, const unsigned short* __restrict__ Bt,
    const float* __restrict__ bias, float* __restrict__ fout) {
  const int tid = threadIdx.x;
  const int n0 = blockIdx.x * 128, m0 = blockIdx.y * 128;

  __shared__ __align__(16) unsigned short lA[128 * 64];
  __shared__ __align__(16) unsigned short lB[128 * 64];

  const int lane = tid & 63, w = tid >> 6;
  const int wr = w >> 1, wc = w & 1;
  const int r = lane & 15, qd = lane >> 4;
  const int srow = tid >> 3, sg = tid & 7;

  f32x4 acc[4][4];
#pragma unroll
  for (int i = 0; i < 4; i++)
#pragma unroll
    for (int j = 0; j < 4; j++) acc[i][j] = (f32x4){0.f, 0.f, 0.f, 0.f};

  for (int k0 = 0; k0 < 1024; k0 += 64) {
    __syncthreads();
#pragma unroll
    for (int p = 0; p < 4; p++) {
      int row = p * 32 + srow;
      int gs = sg ^ (row & 7);
      gld16(&A[(size_t)(m0 + row) * 1024 + k0 + gs * 8], &lA[row * 64 + sg * 8]);
      gld16(&Bt[(size_t)(n0 + row) * 1024 + k0 + gs * 8], &lB[row * 64 + sg * 8]);
    }
    __syncthreads();
#pragma unroll
    for (int kf = 0; kf < 2; kf++) {
      bf16x8 af[4], bfr[4];
#pragma unroll
      for (int mt = 0; mt < 4; mt++) {
        int row = wr * 64 + mt * 16 + r;
        int lg = (kf * 4 + qd) ^ (row & 7);
        af[mt] = *(const bf16x8*)&lA[row * 64 + lg * 8];
      }
#pragma unroll
      for (int nt = 0; nt < 4; nt++) {
        int row = wc * 64 + nt * 16 + r;
        int lg = (kf * 4 + qd) ^ (row & 7);
        bfr[nt] = *(const bf16x8*)&lB[row * 64 + lg * 8];
      }
#pragma unroll
      for (int mt = 0; mt < 4; mt++)
#pragma unroll
        for (int nt = 0; nt < 4; nt++)
          acc[mt][nt] = __builtin_amdgcn_mfma_f32_16x16x32_bf16(af[mt], bfr[nt],
                                                               acc[mt][nt], 0, 0, 0);
    }
  }

#pragma unroll
  for (int nt = 0; nt < 4; nt++) {
    int n = n0 + wc * 64 + nt * 16 + r;
    float bv = bias[n];
#pragma unroll
    for (int mt = 0; mt < 4; mt++) {
      int mg = m0 + wr * 64 + mt * 16 + qd * 4;
      f32x4 a = acc[mt][nt];
      fout[(size_t)(mg + 0) * 1024 + n] = a.x + bv;
      fout[(size_t)(mg + 1) * 1024 + n] = a.y + bv;
      fout[(size_t)(mg + 2) * 1024 + n] = a.z + bv;
      fout[(size_t)(mg + 3) * 1024 + n] = a.w + bv;
    }
  }
}

// ---------------- flash attention (no-max softmax) + fused q-maxpool ----------------
__global__ __launch_bounds__(256) void k_attn(const unsigned short* __restrict__ Qp,
                                              const unsigned short* __restrict__ Kp,
                                              const unsigned short* __restrict__ Vt,
                                              unsigned short* __restrict__ Am) {
  const int tid = threadIdx.x;
  const int qt = blockIdx.x, bh = blockIdx.y;
  const int w = tid >> 6, lane = tid & 63;
  const int r = lane & 15, qd = lane >> 4;
  const int srow = tid >> 3, sg = tid & 7;

  __shared__ __align__(16) unsigned short lK[64 * 64];
  __shared__ __align__(16) unsigned short lV[64 * 64];
  __shared__ __align__(16) unsigned short lP[4][16 * 80];

  const int q0 = qt * 64;
  const int qrow = q0 + w * 16 + r;
  const size_t qbase = ((size_t)bh * 2048 + qrow) * 64;
  const bf16x8 bq0 = *(const bf16x8*)&Qp[qbase + qd * 8];
  const bf16x8 bq1 = *(const bf16x8*)&Qp[qbase + 32 + qd * 8];

  const unsigned short* Kg = Kp + (size_t)bh * 2048 * 64;
  const unsigned short* Vg = Vt + (size_t)bh * 64 * 2048;

  const float K2 = 0.125f * 1.44269504f;

  float lsum = 0.f;
  f32x4 accO[4];
#pragma unroll
  for (int i = 0; i < 4; i++) accO[i] = (f32x4){0.f, 0.f, 0.f, 0.f};

  char* lPw = (char*)&lP[w][0];

  for (int kb = 0; kb < 2048; kb += 64) {
    __syncthreads();
#pragma unroll
    for (int c = 0; c < 2; c++) {
      int row = c * 32 + srow;
      int gs = sg ^ (row & 7);
      gld16(&Kg[(size_t)(kb + row) * 64 + gs * 8], &lK[row * 64 + sg * 8]);
      gld16(&Vg[(size_t)row * 2048 + kb + gs * 8], &lV[row * 64 + sg * 8]);
    }
    __syncthreads();

    f32x4 s[4];
#pragma unroll
    for (int mt = 0; mt < 4; mt++) {
      int row = mt * 16 + r;
      int lg0 = qd ^ (row & 7), lg1 = (4 + qd) ^ (row & 7);
      bf16x8 ak0 = *(const bf16x8*)&lK[row * 64 + lg0 * 8];
      bf16x8 ak1 = *(const bf16x8*)&lK[row * 64 + lg1 * 8];
      s[mt] = (f32x4){0.f, 0.f, 0.f, 0.f};
      s[mt] = __builtin_amdgcn_mfma_f32_16x16x32_bf16(ak0, bq0, s[mt], 0, 0, 0);
      s[mt] = __builtin_amdgcn_mfma_f32_16x16x32_bf16(ak1, bq1, s[mt], 0, 0, 0);
    }

#pragma unroll
    for (int mt = 0; mt < 4; mt++) {
      float p0 = __builtin_amdgcn_exp2f(fmaf(s[mt][0], K2, -0.5f));
      float p1 = __builtin_amdgcn_exp2f(fmaf(s[mt][1], K2, -0.5f));
      float p2 = __builtin_amdgcn_exp2f(fmaf(s[mt][2], K2, -0.5f));
      float p3 = __builtin_amdgcn_exp2f(fmaf(s[mt][3], K2, -0.5f));
      lsum += (p0 + p1) + (p2 + p3);
      uint2 dw; dw.x = pk2bf(p0, p1); dw.y = pk2bf(p2, p3);
      int off = r * 160 + (((2 * mt + (qd >> 1)) ^ (r & 7)) << 4) + ((qd & 1) << 3);
      *(uint2*)(lPw + off) = dw;
    }

    bf16x8 ap0 = *(const bf16x8*)(lPw + r * 160 + ((qd ^ (r & 7)) << 4));
    bf16x8 ap1 = *(const bf16x8*)(lPw + r * 160 + (((4 + qd) ^ (r & 7)) << 4));

#pragma unroll
    for (int nt = 0; nt < 4; nt++) {
      int row = nt * 16 + r;
      int lg0 = qd ^ (row & 7), lg1 = (4 + qd) ^ (row & 7);
      bf16x8 bv0 = *(const bf16x8*)&lV[row * 64 + lg0 * 8];
      bf16x8 bv1 = *(const bf16x8*)&lV[row * 64 + lg1 * 8];
      accO[nt] = __builtin_amdgcn_mfma_f32_16x16x32_bf16(ap0, bv0, accO[nt], 0, 0, 0);
      accO[nt] = __builtin_amdgcn_mfma_f32_16x16x32_bf16(ap1, bv1, accO[nt], 0, 0, 0);
    }
  }

  lsum += __shfl_xor(lsum, 16, 64);
  lsum += __shfl_xor(lsum, 32, 64);
  float linv = 1.f / lsum;
  float inv[4];
#pragma unroll
  for (int g = 0; g < 4; g++) inv[g] = __shfl(linv, qd * 4 + g, 64);

#pragma unroll
  for (int nt = 0; nt < 4; nt++) {
    int d = nt * 16 + r;
    int s4 = (q0 + w * 16 + qd * 4) >> 1;
    float o0 = fmaxf(accO[nt][0] * inv[0], accO[nt][1] * inv[1]);
    float o1 = fmaxf(accO[nt][2] * inv[2], accO[nt][3] * inv[3]);
    size_t base = ((size_t)bh * 1024 + s4) * 64 + d;
    Am[base] = f2bf(o0);
    Am[base + 64] = f2bf(o1);
  }
}

extern "C" void kernel_launch(void* const* d_in, const int* in_sizes, int n_in,
                              void* d_out, int out_size, void* d_ws, size_t ws_size,
                              hipStream_t stream) {
  const float* x  = (const float*)d_in[0];
  const float* Wq = (const float*)d_in[1];
  const float* bq = (const float*)d_in[2];
  const float* Wk = (const float*)d_in[3];
  const float* bk = (const float*)d_in[4];
  const float* Wv = (const float*)d_in[5];
  const float* bv = (const float*)d_in[6];
  const float* Wo = (const float*)d_in[7];
  const float* bo = (const float*)d_in[8];
  float* out = (float*)d_out;

  uint8_t* ws = (uint8_t*)d_ws;
  uint8_t*        x8  = ws;                                  // 16,777,216 B
  uint8_t*        W8  = ws + 16777216;                       //  3,145,728 B
  unsigned short* WoT = (unsigned short*)(ws + 19922944);    //  2,097,152 B
  unsigned short* Qp  = (unsigned short*)(ws + 22020096);    // 16,777,216 B
  unsigned short* Kp  = (unsigned short*)(ws + 38797312);    // 16,777,216 B
  unsigned short* Vt  = (unsigned short*)(ws + 55574528);    // 16,777,216 B
  unsigned short* Am  = (unsigned short*)(ws + 72351744);    //  8,388,608 B

  k_cvt_x<<<8192, 256, 0, stream>>>(x, x8);
  k_cvt_w<<<dim3(32, 32, 4), dim3(32, 8), 0, stream>>>(Wq, Wk, Wv, Wo, W8, WoT);
  k_gemm_qkv<<<dim3(8, 128, 3), 256, 0, stream>>>(x8, W8, bq, bk, bv, Qp, Kp, Vt);
  k_attn<<<dim3(32, 64), 256, 0, stream>>>(Qp, Kp, Vt, Am);
  k_gemm_out<<<dim3(8, 32), 256, 0, stream>>>(Am, WoT, bo, out);
}